// Round 21
// baseline (31.117 us; speedup 1.0000x reference)
//
#include <hip/hip_runtime.h>
#include <stdint.h>

// Single fused 3x3 neighborhood-attention kernel (R19 + 8-wave blocks).
//  Pass A: block = one image row, 512 threads = 8 waves x 8 channels each,
//    lane = quad (4 px). Per channel: 3 nbr float4 + 1 ref float4 (fully
//    coalesced 1KB/instr), x-margins via __shfl, S-collapsed sumsq.
//  Reduce (3 stages, all in one 40KB buffer):
//    1) fold waves 4..7 into 0..3 (dt+sr via [10][4][256]; s2 via 18 f/lane)
//    2) round A: dt+sr -> threads<256 hold td/tsr
//    3) round B: sq -> tq; softmax; coefs -> LDS
//  Pass B: each wave applies its 8 channels (L3-hot re-read), float4 stores.
//  Rationale: grid is capped at 512 row-blocks (reduce needs all channels),
//  so 2 blocks/CU is a GRID cap; 8-wave blocks double resident waves to
//  16/CU (50%) with the identical proven load shape.
// Shapes: [b=2, c=64, h=256, w=256] fp32.

constexpr int C = 64, H = 256, W = 256, HW = H * W;
constexpr int B = 2;

__global__ __launch_bounds__(512, 2) void fused_kernel(const float* __restrict__ nbr,
                                                       const float* __restrict__ ref,
                                                       float* __restrict__ out) {
  __shared__ float buf[10][4][W];     // 40,960 B; multipurpose

  const int tid  = threadIdx.x;       // 0..511
  const int lane = tid & 63;
  const int wv   = tid >> 6;          // wave 0..7
  const int x0   = lane * 4;

  // XCD band swizzle: 512 blocks, bijective
  const int by = ((blockIdx.x & 7) << 6) | (blockIdx.x >> 3);
  const int b  = by >> 8;
  const int y  = by & 255;
  const int ym = (y == 0)     ? 1     : y - 1;   // jnp reflect
  const int yp = (y == H - 1) ? H - 2 : y + 1;

  const float* nbase = nbr + (size_t)b * C * HW;
  const float* rrow  = ref + (size_t)b * C * HW + y * W;
  float*       obase = out + (size_t)b * C * HW + y * W;
  const int oM = ym * W, oC = y * W, oP = yp * W;
  const int c0 = wv * 8;              // this wave's 8 channels

  // ================= Pass A: accumulate =================
  float dt[4][9], s2[3][6], sr[4];
#pragma unroll
  for (int e = 0; e < 4; ++e) {
    sr[e] = 0.f;
#pragma unroll
    for (int k = 0; k < 9; ++k) dt[e][k] = 0.f;
  }
#pragma unroll
  for (int r = 0; r < 3; ++r)
#pragma unroll
    for (int i = 0; i < 6; ++i) s2[r][i] = 0.f;

#pragma unroll 4
  for (int cc = 0; cc < 8; ++cc) {
    const float* cb = nbase + (size_t)(c0 + cc) * HW;
    const float4 am = *(const float4*)(cb + oM + x0);
    const float4 ac = *(const float4*)(cb + oC + x0);
    const float4 ap = *(const float4*)(cb + oP + x0);
    const float4 rf = *(const float4*)(rrow + (size_t)(c0 + cc) * HW + x0);
    const float rfe[4] = {rf.x, rf.y, rf.z, rf.w};
    sr[0] = fmaf(rfe[0], rfe[0], sr[0]);
    sr[1] = fmaf(rfe[1], rfe[1], sr[1]);
    sr[2] = fmaf(rfe[2], rfe[2], sr[2]);
    sr[3] = fmaf(rfe[3], rfe[3], sr[3]);
    const float4 rows[3] = {am, ac, ap};
#pragma unroll
    for (int r = 0; r < 3; ++r) {
      const float4 v = rows[r];
      float L = __shfl(v.w, lane - 1);
      float R = __shfl(v.x, lane + 1);
      if (lane == 0)  L = v.y;        // reflect: x=-1 -> 1
      if (lane == 63) R = v.z;        // reflect: x=256 -> 254
      const float win[6] = {L, v.x, v.y, v.z, v.w, R};
#pragma unroll
      for (int i = 0; i < 6; ++i) s2[r][i] = fmaf(win[i], win[i], s2[r][i]);
      const int kb = r * 3;
#pragma unroll
      for (int e = 0; e < 4; ++e)
#pragma unroll
        for (int cx = 0; cx < 3; ++cx)
          dt[e][kb + cx] = fmaf(rfe[e], win[e + cx], dt[e][kb + cx]);
    }
  }

  // ---- stage 1: fold waves 4..7 into waves 0..3 ----
  if (wv >= 4) {
#pragma unroll
    for (int k = 0; k < 9; ++k)
      *(float4*)&buf[k][wv - 4][x0] = float4{dt[0][k], dt[1][k], dt[2][k], dt[3][k]};
    *(float4*)&buf[9][wv - 4][x0] = float4{sr[0], sr[1], sr[2], sr[3]};
  }
  __syncthreads();
  if (wv < 4) {
#pragma unroll
    for (int k = 0; k < 9; ++k) {
      const float4 t = *(const float4*)&buf[k][wv][x0];
      dt[0][k] += t.x; dt[1][k] += t.y; dt[2][k] += t.z; dt[3][k] += t.w;
    }
    const float4 t9 = *(const float4*)&buf[9][wv][x0];
    sr[0] += t9.x; sr[1] += t9.y; sr[2] += t9.z; sr[3] += t9.w;
  }
  __syncthreads();
  // s2 fold: 18 floats per lane, stride 18 (2-way bank alias = free)
  float* s2b = &buf[0][0][0];
  if (wv >= 4) {
    float* p = s2b + ((size_t)((wv - 4) * 64 + lane)) * 18;
#pragma unroll
    for (int r = 0; r < 3; ++r)
#pragma unroll
      for (int i = 0; i < 6; ++i) p[r * 6 + i] = s2[r][i];
  }
  __syncthreads();
  if (wv < 4) {
    const float* p = s2b + ((size_t)(wv * 64 + lane)) * 18;
#pragma unroll
    for (int r = 0; r < 3; ++r)
#pragma unroll
      for (int i = 0; i < 6; ++i) s2[r][i] += p[r * 6 + i];
  }
  __syncthreads();

  // ---- stage 2 round A: dt + sr (waves 0..3 write; threads<256 read) ----
  if (wv < 4) {
#pragma unroll
    for (int k = 0; k < 9; ++k)
      *(float4*)&buf[k][wv][x0] = float4{dt[0][k], dt[1][k], dt[2][k], dt[3][k]};
    *(float4*)&buf[9][wv][x0] = float4{sr[0], sr[1], sr[2], sr[3]};
  }
  __syncthreads();
  float td[9] = {0,0,0,0,0,0,0,0,0};
  float tsr = 0.f;
  if (tid < W) {
#pragma unroll
    for (int k = 0; k < 9; ++k)
      td[k] = buf[k][0][tid] + buf[k][1][tid] + buf[k][2][tid] + buf[k][3][tid];
    tsr = buf[9][0][tid] + buf[9][1][tid] + buf[9][2][tid] + buf[9][3][tid];
  }
  __syncthreads();

  // ---- stage 2 round B: sq (expanded from s2) ----
  if (wv < 4) {
#pragma unroll
    for (int k = 0; k < 9; ++k) {
      const int r = k / 3, cx = k % 3;   // sq[e][k] = s2[r][e+cx]
      *(float4*)&buf[k][wv][x0] = float4{s2[r][cx], s2[r][cx + 1], s2[r][cx + 2], s2[r][cx + 3]};
    }
  }
  __syncthreads();
  float cfw[9] = {0,0,0,0,0,0,0,0,0};
  if (tid < W) {
    float tq[9];
#pragma unroll
    for (int k = 0; k < 9; ++k)
      tq[k] = buf[k][0][tid] + buf[k][1][tid] + buf[k][2][tid] + buf[k][3][tid];
    const float invr = __frsqrt_rn(fmaxf(tsr, 1e-24f));
    float d[9], invp[9];
    float mx = -INFINITY;
#pragma unroll
    for (int k = 0; k < 9; ++k) {
      invp[k] = __frsqrt_rn(fmaxf(tq[k], 1e-24f));
      d[k]    = td[k] * invr * invp[k];
      mx      = fmaxf(mx, d[k]);
    }
    float s = 0.f;
#pragma unroll
    for (int k = 0; k < 9; ++k) {
      cfw[k] = __expf(d[k] - mx);
      s += cfw[k];
    }
    const float sinv = 1.0f / s;
#pragma unroll
    for (int k = 0; k < 9; ++k) cfw[k] *= sinv * invp[k];   // patch l2norm folded
  }
  __syncthreads();   // all round-B reads done; safe to overwrite with coefs

  float* wc = &buf[0][0][0];           // coefs: wc[k*256 + px]  (9KB)
  if (tid < W) {
#pragma unroll
    for (int k = 0; k < 9; ++k) wc[k * W + tid] = cfw[k];
  }
  __syncthreads();

  // ================= Pass B: apply (L2/L3-hot re-read) =================
  float4 cf4[9];
#pragma unroll
  for (int k = 0; k < 9; ++k) cf4[k] = *(const float4*)&wc[k * W + x0];

#pragma unroll 2
  for (int cc = 0; cc < 8; ++cc) {
    const int c = c0 + cc;
    const float* cb = nbase + (size_t)c * HW;
    const float4 am = *(const float4*)(cb + oM + x0);
    const float4 ac = *(const float4*)(cb + oC + x0);
    const float4 ap = *(const float4*)(cb + oP + x0);
    const float4 rf = *(const float4*)(rrow + (size_t)c * HW + x0);

    float agg[4] = {0.f, 0.f, 0.f, 0.f};
    const float4 rows[3] = {am, ac, ap};
#pragma unroll
    for (int r = 0; r < 3; ++r) {
      const float4 v = rows[r];
      float L = __shfl(v.w, lane - 1);
      float R = __shfl(v.x, lane + 1);
      if (lane == 0)  L = v.y;
      if (lane == 63) R = v.z;
      const float win[6] = {L, v.x, v.y, v.z, v.w, R};
#pragma unroll
      for (int cx = 0; cx < 3; ++cx) {
        const float4 cf = cf4[r * 3 + cx];
        const float cfe[4] = {cf.x, cf.y, cf.z, cf.w};
#pragma unroll
        for (int e = 0; e < 4; ++e)
          agg[e] = fmaf(cfe[e], win[e + cx], agg[e]);
      }
    }
    const float ctr[4] = {ac.x, ac.y, ac.z, ac.w};
    const float rfe[4] = {rf.x, rf.y, rf.z, rf.w};
    float oe[4];
#pragma unroll
    for (int e = 0; e < 4; ++e) {
      const float da = ctr[e] - rfe[e];
      oe[e] = agg[e] * __expf(-(da * da));   // exp(ALPHA*(nbr-ref)^2), ALPHA=-1
    }
    float4 o4;
    o4.x = oe[0]; o4.y = oe[1]; o4.z = oe[2]; o4.w = oe[3];
    *(float4*)(obase + (size_t)c * HW + x0) = o4;
  }
}

extern "C" void kernel_launch(void* const* d_in, const int* in_sizes, int n_in,
                              void* d_out, int out_size, void* d_ws, size_t ws_size,
                              hipStream_t stream) {
  const float* nbr = (const float*)d_in[0];
  const float* ref = (const float*)d_in[1];
  float*       out = (float*)d_out;
  fused_kernel<<<dim3(B * H), dim3(512), 0, stream>>>(nbr, ref, out);   // 512 row-blocks
}